// Round 4
// baseline (2249.845 us; speedup 1.0000x reference)
//
#include <hip/hip_runtime.h>
#include <hip/hip_bf16.h>

#define BB 2
#define NN 4096
#define CC 512
#define HH 8
#define DD 64
#define KPIV 512
#define SCALE 0.125f

typedef unsigned short ushort_t;

__device__ __forceinline__ float bf2f(unsigned short h) {
    union { unsigned u; float f; } x; x.u = ((unsigned)h) << 16; return x.f;
}
__device__ __forceinline__ ushort_t f2bf(float f) {
    __hip_bfloat16 h = __float2bfloat16(f);
    ushort_t u;
    __builtin_memcpy(&u, &h, sizeof(u));
    return u;
}

// ---------------- K1: QKV projection GEMM (all fp32) ------------------------
// x: [B*N, C] fp32, w: [C, 3C] fp32 -> q,k fp32 [B,H,N,D], v bf16 [B,H,N,D]
__global__ __launch_bounds__(256) void qkv_gemm_k(
    const float* __restrict__ x, const float* __restrict__ w,
    float* __restrict__ q, float* __restrict__ k, ushort_t* __restrict__ v)
{
    __shared__ float xs[32][68];   // [kk][m] transposed x tile
    __shared__ float ws[32][68];   // [kk][n]
    const int t = threadIdx.x;
    const int row0 = blockIdx.x * 64;
    const int col0 = blockIdx.y * 64;
    const int tr = t & 15, tc = t >> 4;
    // column block is 64-aligned: tensor-select and head are block-constant
    const int ts = col0 >> 9;            // 0=q 1=k 2=v
    const int hh = (col0 >> 6) & 7;
    float acc[4][4] = {};
    for (int k0 = 0; k0 < CC; k0 += 32) {
        __syncthreads();
        // stage x tile 64 rows x 32 cols (fp32), transposed into LDS
        #pragma unroll
        for (int f = t; f < 512; f += 256) {
            const int m = f >> 3, c4 = (f & 7) * 4;
            float4 r = *(const float4*)(x + (size_t)(row0 + m) * CC + k0 + c4);
            xs[c4 + 0][m] = r.x; xs[c4 + 1][m] = r.y;
            xs[c4 + 2][m] = r.z; xs[c4 + 3][m] = r.w;
        }
        // stage w tile 32 rows x 64 cols (fp32)
        #pragma unroll
        for (int f = t; f < 512; f += 256) {
            const int kk = f >> 4, n4 = (f & 15) * 4;
            *(float4*)&ws[kk][n4] =
                *(const float4*)(w + (size_t)(k0 + kk) * (3 * CC) + col0 + n4);
        }
        __syncthreads();
        #pragma unroll
        for (int kk = 0; kk < 32; ++kk) {
            float4 a4 = *(const float4*)&xs[kk][tr * 4];
            float4 b4 = *(const float4*)&ws[kk][tc * 4];
            float av[4] = {a4.x, a4.y, a4.z, a4.w};
            float bv[4] = {b4.x, b4.y, b4.z, b4.w};
            #pragma unroll
            for (int i = 0; i < 4; ++i)
                #pragma unroll
                for (int j = 0; j < 4; ++j)
                    acc[i][j] = fmaf(av[i], bv[j], acc[i][j]);
        }
    }
    #pragma unroll
    for (int i = 0; i < 4; ++i) {
        const int grow = row0 + tr * 4 + i;
        const int b = grow >> 12, n = grow & (NN - 1);
        const size_t base = (((size_t)b * HH + hh) * NN + n) * DD + tc * 4;
        if (ts < 2) {
            float* dst = ts ? k : q;
            float4 val; val.x = acc[i][0]; val.y = acc[i][1]; val.z = acc[i][2]; val.w = acc[i][3];
            *(float4*)(dst + base) = val;
        } else {
            unsigned p0 = ((unsigned)f2bf(acc[i][0])) | (((unsigned)f2bf(acc[i][1])) << 16);
            unsigned p1 = ((unsigned)f2bf(acc[i][2])) | (((unsigned)f2bf(acc[i][3])) << 16);
            uint2 pk; pk.x = p0; pk.y = p1;
            *(uint2*)(v + base) = pk;
        }
    }
}

// ---------------- K2: pass A — per-row softmax denominator l (fp64) ---------
// no max-subtraction: |s|<~8 so exp(s) is safe in fp32; l accumulated fp64
__global__ __launch_bounds__(256) void pass_a_k(
    const float* __restrict__ q, const float* __restrict__ k,
    double* __restrict__ l)
{
    __shared__ float ks[128][68];
    __shared__ double lred[4][64];
    const int t = threadIdx.x;
    const int lane = t & 63, wave = t >> 6;
    const int bh = blockIdx.x >> 6;
    const int q0 = (blockIdx.x & 63) * 64;
    float qr[64];
    {
        const float* qp = q + ((size_t)bh * NN + q0 + lane) * DD;
        #pragma unroll
        for (int i = 0; i < 16; ++i) {
            float4 tmp = *(const float4*)(qp + i * 4);
            qr[4*i] = tmp.x; qr[4*i+1] = tmp.y; qr[4*i+2] = tmp.z; qr[4*i+3] = tmp.w;
        }
    }
    double lcur = 0.0;
    for (int n0 = 0; n0 < NN; n0 += 128) {
        __syncthreads();
        const float* kp = k + ((size_t)bh * NN + n0) * DD;
        for (int f = t; f < 2048; f += 256) {
            const int c = f >> 4, d4 = (f & 15) * 4;
            *(float4*)&ks[c][d4] = *(const float4*)(kp + (size_t)c * DD + d4);
        }
        __syncthreads();
        #pragma unroll 2
        for (int cc = 0; cc < 32; ++cc) {
            const int c = wave * 32 + cc;
            float s0 = 0, s1 = 0, s2 = 0, s3 = 0;
            #pragma unroll
            for (int d4 = 0; d4 < 16; ++d4) {
                float4 kv = *(const float4*)&ks[c][d4 * 4];
                s0 = fmaf(qr[d4*4+0], kv.x, s0);
                s1 = fmaf(qr[d4*4+1], kv.y, s1);
                s2 = fmaf(qr[d4*4+2], kv.z, s2);
                s3 = fmaf(qr[d4*4+3], kv.w, s3);
            }
            const float s = (((s0 + s1) + (s2 + s3))) * SCALE;
            lcur += (double)__expf(s);
        }
    }
    lred[wave][lane] = lcur;
    __syncthreads();
    if (t < 64) {
        double ll = lred[0][t] + lred[1][t] + lred[2][t] + lred[3][t];
        l[(size_t)bh * NN + q0 + t] = ll;
    }
}

// ---------------- K3: pass B — recompute S, P; column-sum partials ----------
// block = (bh, 128 q-rows). lane = q-row (2 rows/lane), wave = column subset.
// per column: cross-lane butterfly sum of 128 p-values -> one fp32 partial.
__global__ __launch_bounds__(256, 2) void pass_b_k(
    const float* __restrict__ q, const float* __restrict__ k,
    const double* __restrict__ l, float* __restrict__ colsum)
{
    __shared__ float ks[128][68];
    const int t = threadIdx.x;
    const int lane = t & 63, wave = t >> 6;
    const int bh = blockIdx.x >> 5;
    const int q0 = (blockIdx.x & 31) * 128;
    float qa[64], qb[64];
    {
        const float* qp = q + ((size_t)bh * NN + q0 + lane) * DD;
        const float* qp2 = qp + (size_t)64 * DD;
        #pragma unroll
        for (int i = 0; i < 16; ++i) {
            float4 ta = *(const float4*)(qp + i * 4);
            float4 tb = *(const float4*)(qp2 + i * 4);
            qa[4*i] = ta.x; qa[4*i+1] = ta.y; qa[4*i+2] = ta.z; qa[4*i+3] = ta.w;
            qb[4*i] = tb.x; qb[4*i+1] = tb.y; qb[4*i+2] = tb.z; qb[4*i+3] = tb.w;
        }
    }
    const float rla = (float)(1.0 / l[(size_t)bh * NN + q0 + lane]);
    const float rlb = (float)(1.0 / l[(size_t)bh * NN + q0 + 64 + lane]);
    for (int n0 = 0; n0 < NN; n0 += 128) {
        __syncthreads();
        const float* kp = k + ((size_t)bh * NN + n0) * DD;
        for (int f = t; f < 2048; f += 256) {
            const int c = f >> 4, d4 = (f & 15) * 4;
            *(float4*)&ks[c][d4] = *(const float4*)(kp + (size_t)c * DD + d4);
        }
        __syncthreads();
        #pragma unroll 2
        for (int cc = 0; cc < 32; ++cc) {
            const int c = wave * 32 + cc;
            float a0 = 0, a1 = 0, a2 = 0, a3 = 0;
            float b0 = 0, b1 = 0, b2 = 0, b3 = 0;
            #pragma unroll
            for (int d4 = 0; d4 < 16; ++d4) {
                float4 kv = *(const float4*)&ks[c][d4 * 4];
                a0 = fmaf(qa[d4*4+0], kv.x, a0);
                a1 = fmaf(qa[d4*4+1], kv.y, a1);
                a2 = fmaf(qa[d4*4+2], kv.z, a2);
                a3 = fmaf(qa[d4*4+3], kv.w, a3);
                b0 = fmaf(qb[d4*4+0], kv.x, b0);
                b1 = fmaf(qb[d4*4+1], kv.y, b1);
                b2 = fmaf(qb[d4*4+2], kv.z, b2);
                b3 = fmaf(qb[d4*4+3], kv.w, b3);
            }
            const float sa = (((a0 + a1) + (a2 + a3))) * SCALE;
            const float sb = (((b0 + b1) + (b2 + b3))) * SCALE;
            float ptot = __expf(sa) * rla + __expf(sb) * rlb;
            #pragma unroll
            for (int off = 1; off < 64; off <<= 1)
                ptot += __shfl_xor(ptot, off);
            if (lane == 0)
                colsum[(size_t)blockIdx.x * NN + n0 + c] = ptot;
        }
    }
}

// ---------------- K4: reduce partials -> importance (fp64) ------------------
__global__ __launch_bounds__(256) void imp_reduce_k(
    const float* __restrict__ colsum, double* __restrict__ imp)
{
    const int n = blockIdx.x * 256 + threadIdx.x;   // 0..8191
    const int b = n >> 12, c = n & (NN - 1);
    const float* p = colsum + (size_t)b * 256 * NN + c;
    double s = 0.0;
    for (int i = 0; i < 256; ++i) s += (double)p[(size_t)i * NN];
    imp[n] = s * (1.0 / (double)(HH * NN));
}

// ---------------- K5: exact top-K via full bitonic sort on fp64 keys --------
// total order: value desc, index asc  == jax.lax.top_k semantics
__global__ __launch_bounds__(1024) void topk_k(
    const double* __restrict__ imp, int* __restrict__ idxout)
{
    __shared__ double sv[4096];
    __shared__ int si[4096];
    const int b = blockIdx.x, t = threadIdx.x;
    for (int i = t; i < 4096; i += 1024) { sv[i] = imp[b * 4096 + i]; si[i] = i; }
    __syncthreads();
    for (int kk = 2; kk <= 4096; kk <<= 1) {
        for (int j = kk >> 1; j > 0; j >>= 1) {
            #pragma unroll 1
            for (int r = 0; r < 2; ++r) {
                const int cm = t + r * 1024;
                const int i = ((cm & ~(j - 1)) << 1) | (cm & (j - 1));
                const int lo = i | j;
                const bool up = ((i & kk) == 0);
                const double va = sv[i], vb = sv[lo];
                const int ia = si[i], ib = si[lo];
                const bool after = (va < vb) || (va == vb && ia > ib);
                if (after == up) { sv[i] = vb; sv[lo] = va; si[i] = ib; si[lo] = ia; }
            }
            __syncthreads();
        }
    }
    if (t < KPIV) idxout[b * KPIV + t] = si[t];
}

// ---------------- K6: O = P@V for pivot rows only ---------------------------
// grid 128 = b(2) x h(8) x chunk(8 of 64 pivot rows); lane = pivot row
__global__ __launch_bounds__(256) void pass_c_k(
    const float* __restrict__ q, const float* __restrict__ k,
    const ushort_t* __restrict__ v, const double* __restrict__ l,
    const int* __restrict__ idx, float* __restrict__ opiv)
{
    __shared__ float ks[64][68];
    __shared__ float vs[64][68];
    __shared__ float ps[64][68];
    const int t = threadIdx.x;
    const int lane = t & 63, wave = t >> 6;
    const int bid = blockIdx.x;
    const int b = bid >> 6, h = (bid >> 3) & 7, chunk = bid & 7;
    const int bh = b * HH + h;
    const int r0 = chunk * 64;
    const int tok = idx[b * KPIV + r0 + lane];
    float qr[64];
    {
        const float* qp = q + ((size_t)bh * NN + tok) * DD;
        #pragma unroll
        for (int i = 0; i < 16; ++i) {
            float4 tmp = *(const float4*)(qp + i * 4);
            qr[4*i] = tmp.x; qr[4*i+1] = tmp.y; qr[4*i+2] = tmp.z; qr[4*i+3] = tmp.w;
        }
    }
    const float rl = (float)(1.0 / l[(size_t)bh * NN + tok]);
    const int tq = (t & 15) * 4;
    const int td = (t >> 4) * 4;
    float acc[4][4] = {};
    for (int n0 = 0; n0 < NN; n0 += 64) {
        __syncthreads();
        const float* kp = k + ((size_t)bh * NN + n0) * DD;
        const ushort_t* vp = v + ((size_t)bh * NN + n0) * DD;
        for (int f = t; f < 1024; f += 256) {
            const int c = f >> 4, d4 = (f & 15) * 4;
            *(float4*)&ks[c][d4] = *(const float4*)(kp + (size_t)c * DD + d4);
            uint2 rv = *(const uint2*)(vp + (size_t)c * DD + d4);
            vs[c][d4+0] = bf2f(rv.x & 0xffff);
            vs[c][d4+1] = bf2f(rv.x >> 16);
            vs[c][d4+2] = bf2f(rv.y & 0xffff);
            vs[c][d4+3] = bf2f(rv.y >> 16);
        }
        __syncthreads();
        #pragma unroll 2
        for (int cc = 0; cc < 16; ++cc) {
            const int c = wave * 16 + cc;
            float s0 = 0, s1 = 0, s2 = 0, s3 = 0;
            #pragma unroll
            for (int d4 = 0; d4 < 16; ++d4) {
                float4 kv = *(const float4*)&ks[c][d4 * 4];
                s0 = fmaf(qr[d4*4+0], kv.x, s0);
                s1 = fmaf(qr[d4*4+1], kv.y, s1);
                s2 = fmaf(qr[d4*4+2], kv.z, s2);
                s3 = fmaf(qr[d4*4+3], kv.w, s3);
            }
            const float s = (((s0 + s1) + (s2 + s3))) * SCALE;
            ps[c][lane] = __expf(s) * rl;
        }
        __syncthreads();
        #pragma unroll 4
        for (int c = 0; c < 64; ++c) {
            float4 p4 = *(const float4*)&ps[c][tq];
            float4 v4 = *(const float4*)&vs[c][td];
            float pv[4] = {p4.x, p4.y, p4.z, p4.w};
            float vv[4] = {v4.x, v4.y, v4.z, v4.w};
            #pragma unroll
            for (int i = 0; i < 4; ++i)
                #pragma unroll
                for (int j = 0; j < 4; ++j)
                    acc[i][j] = fmaf(pv[i], vv[j], acc[i][j]);
        }
    }
    #pragma unroll
    for (int i = 0; i < 4; ++i) {
        float4 val;
        val.x = acc[i][0]; val.y = acc[i][1]; val.z = acc[i][2]; val.w = acc[i][3];
        *(float4*)(opiv + ((size_t)(b * KPIV + r0 + tq + i)) * CC + h * DD + td) = val;
    }
}

// ---------------- K7: output projection of pivot rows -> fp32 out -----------
__global__ __launch_bounds__(256) void proj_k(
    const float* __restrict__ opiv, const float* __restrict__ wp,
    const float* __restrict__ bp, float* __restrict__ out)
{
    __shared__ float os[8][CC];
    const int t = threadIdx.x;
    const int r0 = blockIdx.x * 8;
    for (int f = t; f < 1024; f += 256) {
        const int rr = f >> 7, i = (f & 127) * 4;
        *(float4*)&os[rr][i] = *(const float4*)(opiv + (size_t)(r0 + rr) * CC + i);
    }
    __syncthreads();
    const int c0 = t;
    float acc0[8] = {}, acc1[8] = {};
    for (int i = 0; i < CC; ++i) {
        const float w0 = wp[(size_t)i * CC + c0];
        const float w1 = wp[(size_t)i * CC + c0 + 256];
        #pragma unroll
        for (int rr = 0; rr < 8; ++rr) {
            const float ov = os[rr][i];
            acc0[rr] = fmaf(ov, w0, acc0[rr]);
            acc1[rr] = fmaf(ov, w1, acc1[rr]);
        }
    }
    const float b0 = bp[c0], b1 = bp[c0 + 256];
    #pragma unroll
    for (int rr = 0; rr < 8; ++rr) {
        out[((size_t)(r0 + rr)) * CC + c0]       = acc0[rr] + b0;
        out[((size_t)(r0 + rr)) * CC + c0 + 256] = acc1[rr] + b1;
    }
}

extern "C" void kernel_launch(void* const* d_in, const int* in_sizes, int n_in,
                              void* d_out, int out_size, void* d_ws, size_t ws_size,
                              hipStream_t stream)
{
    const float* x     = (const float*)d_in[0];
    const float* wqkv  = (const float*)d_in[1];
    const float* wproj = (const float*)d_in[2];
    const float* bproj = (const float*)d_in[3];

    // workspace layout: ~53 MB total (q/k fp32, v bf16, l/imp fp64)
    float*    q      = (float*)d_ws;                                  // 16.78 MB
    float*    k      = q + (size_t)BB * HH * NN * DD;                 // 16.78 MB
    ushort_t* v      = (ushort_t*)(k + (size_t)BB * HH * NN * DD);    //  8.39 MB
    double*   l      = (double*)(v + (size_t)BB * HH * NN * DD);      //  0.52 MB
    float*    colsum = (float*)(l + (size_t)BB * HH * NN);            //  8.39 MB
    double*   imp    = (double*)(colsum + (size_t)512 * NN);          //  0.07 MB
    int*      idx    = (int*)(imp + BB * NN);                         //  4 KB
    float*    opiv   = (float*)(idx + BB * KPIV);                     //  2.10 MB
    float*    out    = (float*)d_out;

    // required bytes; if workspace is smaller, bail (out stays 0 -> absmax
    // == max|ref| ~= 0.254 is the diagnostic signature for this path)
    const size_t need = (size_t)((char*)(opiv + (size_t)BB * KPIV * CC) - (char*)d_ws);
    if (ws_size < need) return;

    qkv_gemm_k<<<dim3(128, 24), 256, 0, stream>>>(x, wqkv, q, k, v);
    pass_a_k<<<1024, 256, 0, stream>>>(q, k, l);
    pass_b_k<<<512, 256, 0, stream>>>(q, k, l, colsum);
    imp_reduce_k<<<32, 256, 0, stream>>>(colsum, imp);
    topk_k<<<2, 1024, 0, stream>>>(imp, idx);
    pass_c_k<<<128, 256, 0, stream>>>(q, k, v, l, idx, opiv);
    proj_k<<<128, 256, 0, stream>>>(opiv, wproj, bproj, out);
}

// Round 6
// 1199.800 us; speedup vs baseline: 1.8752x; 1.8752x over previous
//
#include <hip/hip_runtime.h>
#include <hip/hip_bf16.h>

#define BB 2
#define NN 4096
#define CC 512
#define HH 8
#define DD 64
#define KPIV 512
#define SCALE 0.125f

typedef unsigned short ushort_t;
typedef __attribute__((ext_vector_type(8))) short short8;
typedef __attribute__((ext_vector_type(16))) float float16;

__device__ __forceinline__ float bf2f(ushort_t h) {
    union { unsigned u; float f; } x; x.u = ((unsigned)h) << 16; return x.f;
}
__device__ __forceinline__ ushort_t f2bf(float f) {
    __hip_bfloat16 h = __float2bfloat16(f);
    ushort_t u;
    __builtin_memcpy(&u, &h, sizeof(u));
    return u;
}
// 3-term bf16 decomposition: x ~= a+b+c to ~24 mantissa bits (residuals exact in fp32)
__device__ __forceinline__ void split3(float x, short& a, short& b, short& c) {
    const ushort_t h1 = f2bf(x);
    const float r1 = x - bf2f(h1);
    const ushort_t h2 = f2bf(r1);
    const float r2 = r1 - bf2f(h2);
    const ushort_t h3 = f2bf(r2);
    a = (short)h1; b = (short)h2; c = (short)h3;
}

// ---------------- K1: QKV projection GEMM, 128x128 tile, 8x8 reg blocking ---
// x: [B*N, C] fp32, w: [C, 3C] fp32 -> q,k fp32 [B,H,N,D], v bf16 [B,H,N,D]
__global__ __launch_bounds__(256) void qkv_gemm_k(
    const float* __restrict__ x, const float* __restrict__ w,
    float* __restrict__ q, float* __restrict__ k, ushort_t* __restrict__ v)
{
    __shared__ __attribute__((aligned(16))) float xs[16][132];  // [kk][m]
    __shared__ __attribute__((aligned(16))) float ws[16][132];  // [kk][n]
    const int t = threadIdx.x;
    const int row0 = blockIdx.x * 128;
    const int col0 = blockIdx.y * 128;
    const int tr = t & 15, tc = t >> 4;
    const int ts = col0 >> 9;   // tensor select, constant per block
    float acc[8][8] = {};
    for (int k0 = 0; k0 < CC; k0 += 16) {
        __syncthreads();
        {   // stage x tile 128 rows x 16 k, transposed
            const int r = t >> 1, off = (t & 1) * 8;
            const float* xp = x + (size_t)(row0 + r) * CC + k0 + off;
            float4 v0 = *(const float4*)xp;
            float4 v1 = *(const float4*)(xp + 4);
            xs[off + 0][r] = v0.x; xs[off + 1][r] = v0.y;
            xs[off + 2][r] = v0.z; xs[off + 3][r] = v0.w;
            xs[off + 4][r] = v1.x; xs[off + 5][r] = v1.y;
            xs[off + 6][r] = v1.z; xs[off + 7][r] = v1.w;
        }
        {   // stage w tile 16 k x 128 cols
            const int kk = t >> 4, c8 = (t & 15) * 8;
            const float* wp2 = w + (size_t)(k0 + kk) * (3 * CC) + col0 + c8;
            *(float4*)&ws[kk][c8]     = *(const float4*)wp2;
            *(float4*)&ws[kk][c8 + 4] = *(const float4*)(wp2 + 4);
        }
        __syncthreads();
        #pragma unroll
        for (int kk = 0; kk < 16; ++kk) {
            float a[8], b[8];
            *(float4*)&a[0] = *(const float4*)&xs[kk][tr * 8];
            *(float4*)&a[4] = *(const float4*)&xs[kk][tr * 8 + 4];
            *(float4*)&b[0] = *(const float4*)&ws[kk][tc * 8];
            *(float4*)&b[4] = *(const float4*)&ws[kk][tc * 8 + 4];
            #pragma unroll
            for (int i = 0; i < 8; ++i)
                #pragma unroll
                for (int j = 0; j < 8; ++j)
                    acc[i][j] = fmaf(a[i], b[j], acc[i][j]);
        }
    }
    const int gc0 = col0 + tc * 8;
    const int hh = (gc0 >> 6) & 7;
    const int dd0 = gc0 & 63;
    #pragma unroll
    for (int i = 0; i < 8; ++i) {
        const int grow = row0 + tr * 8 + i;
        const int b = grow >> 12, n = grow & (NN - 1);
        const size_t base = (((size_t)b * HH + hh) * NN + n) * DD + dd0;
        if (ts < 2) {
            float* dst = ts ? k : q;
            float4 v0, v1;
            v0.x = acc[i][0]; v0.y = acc[i][1]; v0.z = acc[i][2]; v0.w = acc[i][3];
            v1.x = acc[i][4]; v1.y = acc[i][5]; v1.z = acc[i][6]; v1.w = acc[i][7];
            *(float4*)(dst + base) = v0;
            *(float4*)(dst + base + 4) = v1;
        } else {
            uint4 pk;
            pk.x = ((unsigned)f2bf(acc[i][0])) | (((unsigned)f2bf(acc[i][1])) << 16);
            pk.y = ((unsigned)f2bf(acc[i][2])) | (((unsigned)f2bf(acc[i][3])) << 16);
            pk.z = ((unsigned)f2bf(acc[i][4])) | (((unsigned)f2bf(acc[i][5])) << 16);
            pk.w = ((unsigned)f2bf(acc[i][6])) | (((unsigned)f2bf(acc[i][7])) << 16);
            *(uint4*)(v + base) = pk;
        }
    }
}

// ---------------- shared MFMA S-pass machinery (3x3 split, 6 MFMAs) ---------
// block = 16 bh x 32 qtiles of 128 rows; wave wv owns rows qt*128+wv*32+(lane&31).
// s = q1k1 + (q2k1+q1k2) + (q2k2+q3k1+q1k3); dropped terms <= 2^-24.
// MFMA 32x32x16 layouts: A[m=lane&31][kd=(lane>>5)*8+j], B symmetric,
// C: col=lane&31, row=(reg&3)+8*(reg>>2)+4*(lane>>5)

__device__ __forceinline__ void load_q_frags3(
    const float* __restrict__ q, int bh, int qt, int wv, int ln, int g,
    short8* q1, short8* q2, short8* q3)
{
    const float* qp = q + ((size_t)bh * NN + qt * 128 + wv * 32 + ln) * DD + g * 8;
    #pragma unroll
    for (int c = 0; c < 4; ++c) {
        float4 f0 = *(const float4*)(qp + c * 16);
        float4 f1 = *(const float4*)(qp + c * 16 + 4);
        float xv[8] = {f0.x, f0.y, f0.z, f0.w, f1.x, f1.y, f1.z, f1.w};
        #pragma unroll
        for (int j = 0; j < 8; ++j) {
            short a, b, cc2;
            split3(xv[j] * SCALE, a, b, cc2);   // *0.125 exact (pow2)
            q1[c][j] = a; q2[c][j] = b; q3[c][j] = cc2;
        }
    }
}

__device__ __forceinline__ void stage_k_tile3(
    const float* __restrict__ k, int bh, int n0, int t,
    short8* k1, short8* k2, short8* k3)
{
    const int tok = t & 31, seg = t >> 5;     // d range = seg*8..seg*8+8
    const float* kp = k + ((size_t)bh * NN + n0 + tok) * DD + seg * 8;
    float4 f0 = *(const float4*)kp;
    float4 f1 = *(const float4*)(kp + 4);
    float xv[8] = {f0.x, f0.y, f0.z, f0.w, f1.x, f1.y, f1.z, f1.w};
    short8 h1, h2, h3;
    #pragma unroll
    for (int j = 0; j < 8; ++j) {
        short a, b, c;
        split3(xv[j], a, b, c);
        h1[j] = a; h2[j] = b; h3[j] = c;
    }
    k1[seg * 32 + tok] = h1;
    k2[seg * 32 + tok] = h2;
    k3[seg * 32 + tok] = h3;
}

#define SIX_MFMA(c)                                                        \
    {                                                                      \
        short8 b1 = k1s[((c) * 2 + g) * 32 + ln];                          \
        short8 b2 = k2s[((c) * 2 + g) * 32 + ln];                          \
        short8 b3 = k3s[((c) * 2 + g) * 32 + ln];                          \
        a0  = __builtin_amdgcn_mfma_f32_32x32x16_bf16(q1[c], b1, a0, 0,0,0); \
        ar1 = __builtin_amdgcn_mfma_f32_32x32x16_bf16(q2[c], b1, ar1,0,0,0); \
        ar1 = __builtin_amdgcn_mfma_f32_32x32x16_bf16(q1[c], b2, ar1,0,0,0); \
        ar2 = __builtin_amdgcn_mfma_f32_32x32x16_bf16(q2[c], b2, ar2,0,0,0); \
        ar2 = __builtin_amdgcn_mfma_f32_32x32x16_bf16(q3[c], b1, ar2,0,0,0); \
        ar1 = __builtin_amdgcn_mfma_f32_32x32x16_bf16(q1[c], b3, ar1,0,0,0); \
    }

// ---------------- K2: pass A — per-row softmax denominator l ----------------
__global__ __launch_bounds__(256) void pass_a_k(
    const float* __restrict__ q, const float* __restrict__ k,
    float* __restrict__ l)
{
    __shared__ short8 k1s[8 * 32];
    __shared__ short8 k2s[8 * 32];
    __shared__ short8 k3s[8 * 32];
    const int t = threadIdx.x;
    const int lane = t & 63, wv = t >> 6;
    const int g = lane >> 5, ln = lane & 31;
    const int bh = blockIdx.x >> 5;
    const int qt = blockIdx.x & 31;
    short8 q1[4], q2[4], q3[4];
    load_q_frags3(q, bh, qt, wv, ln, g, q1, q2, q3);
    float rowacc[16];
    #pragma unroll
    for (int r = 0; r < 16; ++r) rowacc[r] = 0.f;
    for (int n0 = 0; n0 < NN; n0 += 32) {
        __syncthreads();
        stage_k_tile3(k, bh, n0, t, k1s, k2s, k3s);
        __syncthreads();
        float16 a0, ar1, ar2;
        #pragma unroll
        for (int i = 0; i < 16; ++i) { a0[i] = 0.f; ar1[i] = 0.f; ar2[i] = 0.f; }
        SIX_MFMA(0) SIX_MFMA(1) SIX_MFMA(2) SIX_MFMA(3)
        #pragma unroll
        for (int r = 0; r < 16; ++r)
            rowacc[r] += __expf(a0[r] + (ar1[r] + ar2[r]));
    }
    // reduce over the 32 columns (lane bits 0..4)
    #pragma unroll
    for (int r = 0; r < 16; ++r) {
        float vs = rowacc[r];
        vs += __shfl_xor(vs, 1);
        vs += __shfl_xor(vs, 2);
        vs += __shfl_xor(vs, 4);
        vs += __shfl_xor(vs, 8);
        vs += __shfl_xor(vs, 16);
        rowacc[r] = vs;
    }
    if (ln == 0) {
        #pragma unroll
        for (int r = 0; r < 16; ++r) {
            const int row = (r & 3) + 8 * (r >> 2) + 4 * g;
            l[(size_t)bh * NN + qt * 128 + wv * 32 + row] = rowacc[r];
        }
    }
}

// ---------------- K3: pass B — column sums of P -> colsum[512][4096] --------
__global__ __launch_bounds__(256) void pass_b_k(
    const float* __restrict__ q, const float* __restrict__ k,
    const float* __restrict__ l, float* __restrict__ colsum)
{
    __shared__ short8 k1s[8 * 32];
    __shared__ short8 k2s[8 * 32];
    __shared__ short8 k3s[8 * 32];
    __shared__ float csbuf[4][32];
    const int t = threadIdx.x;
    const int lane = t & 63, wv = t >> 6;
    const int g = lane >> 5, ln = lane & 31;
    const int bh = blockIdx.x >> 5;
    const int qt = blockIdx.x & 31;
    short8 q1[4], q2[4], q3[4];
    load_q_frags3(q, bh, qt, wv, ln, g, q1, q2, q3);
    float rv[16];
    #pragma unroll
    for (int r = 0; r < 16; ++r) {
        const int row = (r & 3) + 8 * (r >> 2) + 4 * g;
        rv[r] = 1.0f / l[(size_t)bh * NN + qt * 128 + wv * 32 + row];
    }
    for (int n0 = 0; n0 < NN; n0 += 32) {
        __syncthreads();   // prev-step mfma reads + csbuf write complete
        stage_k_tile3(k, bh, n0, t, k1s, k2s, k3s);
        if (n0 > 0 && t < 32)   // drain previous step's column sums
            colsum[(size_t)blockIdx.x * NN + (n0 - 32) + t] =
                (csbuf[0][t] + csbuf[1][t]) + (csbuf[2][t] + csbuf[3][t]);
        __syncthreads();   // staging visible; csbuf consumed
        float16 a0, ar1, ar2;
        #pragma unroll
        for (int i = 0; i < 16; ++i) { a0[i] = 0.f; ar1[i] = 0.f; ar2[i] = 0.f; }
        SIX_MFMA(0) SIX_MFMA(1) SIX_MFMA(2) SIX_MFMA(3)
        float cs = 0.f;
        #pragma unroll
        for (int r = 0; r < 16; ++r)
            cs = fmaf(__expf(a0[r] + (ar1[r] + ar2[r])), rv[r], cs);
        cs += __shfl_xor(cs, 32);   // add other 16-row half (same column)
        if (g == 0) csbuf[wv][ln] = cs;
    }
    __syncthreads();
    if (t < 32)
        colsum[(size_t)blockIdx.x * NN + (NN - 32) + t] =
            (csbuf[0][t] + csbuf[1][t]) + (csbuf[2][t] + csbuf[3][t]);
}

// ---------------- K4: reduce partials -> importance (fp64) ------------------
__global__ __launch_bounds__(256) void imp_reduce_k(
    const float* __restrict__ colsum, double* __restrict__ imp)
{
    const int n = blockIdx.x * 256 + threadIdx.x;   // 0..8191
    const int b = n >> 12, c = n & (NN - 1);
    const float* p = colsum + (size_t)b * 256 * NN + c;
    double s = 0.0;
    for (int i = 0; i < 256; ++i) s += (double)p[(size_t)i * NN];
    imp[n] = s * (1.0 / (double)(HH * NN));
}

// ---------------- K5: exact top-K via full bitonic sort on fp64 keys --------
// total order: value desc, index asc  == jax.lax.top_k semantics
__global__ __launch_bounds__(1024) void topk_k(
    const double* __restrict__ imp, int* __restrict__ idxout)
{
    __shared__ double sv[4096];
    __shared__ int si[4096];
    const int b = blockIdx.x, t = threadIdx.x;
    for (int i = t; i < 4096; i += 1024) { sv[i] = imp[b * 4096 + i]; si[i] = i; }
    __syncthreads();
    for (int kk = 2; kk <= 4096; kk <<= 1) {
        for (int j = kk >> 1; j > 0; j >>= 1) {
            #pragma unroll 1
            for (int r = 0; r < 2; ++r) {
                const int cm = t + r * 1024;
                const int i = ((cm & ~(j - 1)) << 1) | (cm & (j - 1));
                const int lo = i | j;
                const bool up = ((i & kk) == 0);
                const double va = sv[i], vb = sv[lo];
                const int ia = si[i], ib = si[lo];
                const bool after = (va < vb) || (va == vb && ia > ib);
                if (after == up) { sv[i] = vb; sv[lo] = va; si[i] = ib; si[lo] = ia; }
            }
            __syncthreads();
        }
    }
    if (t < KPIV) idxout[b * KPIV + t] = si[t];
}

// ---------------- K6: O = P@V for pivot rows only ---------------------------
// grid 128 = b(2) x h(8) x chunk(8 of 64 pivot rows); lane = pivot row
__global__ __launch_bounds__(256) void pass_c_k(
    const float* __restrict__ q, const float* __restrict__ k,
    const ushort_t* __restrict__ v, const float* __restrict__ l,
    const int* __restrict__ idx, float* __restrict__ opiv)
{
    __shared__ __attribute__((aligned(16))) float ks[64][68];
    __shared__ __attribute__((aligned(16))) float vs[64][68];
    __shared__ __attribute__((aligned(16))) float ps[64][68];
    const int t = threadIdx.x;
    const int lane = t & 63, wave = t >> 6;
    const int bid = blockIdx.x;
    const int b = bid >> 6, h = (bid >> 3) & 7, chunk = bid & 7;
    const int bh = b * HH + h;
    const int r0 = chunk * 64;
    const int tok = idx[b * KPIV + r0 + lane];
    float qr[64];
    {
        const float* qp = q + ((size_t)bh * NN + tok) * DD;
        #pragma unroll
        for (int i = 0; i < 16; ++i) {
            float4 tmp = *(const float4*)(qp + i * 4);
            qr[4*i] = tmp.x; qr[4*i+1] = tmp.y; qr[4*i+2] = tmp.z; qr[4*i+3] = tmp.w;
        }
    }
    const float rl = 1.0f / l[(size_t)bh * NN + tok];
    const int tq = (t & 15) * 4;
    const int td = (t >> 4) * 4;
    float acc[4][4] = {};
    for (int n0 = 0; n0 < NN; n0 += 64) {
        __syncthreads();
        const float* kp = k + ((size_t)bh * NN + n0) * DD;
        const ushort_t* vp = v + ((size_t)bh * NN + n0) * DD;
        for (int f = t; f < 1024; f += 256) {
            const int c = f >> 4, d4 = (f & 15) * 4;
            *(float4*)&ks[c][d4] = *(const float4*)(kp + (size_t)c * DD + d4);
            uint2 rv2 = *(const uint2*)(vp + (size_t)c * DD + d4);
            vs[c][d4+0] = bf2f(rv2.x & 0xffff);
            vs[c][d4+1] = bf2f(rv2.x >> 16);
            vs[c][d4+2] = bf2f(rv2.y & 0xffff);
            vs[c][d4+3] = bf2f(rv2.y >> 16);
        }
        __syncthreads();
        #pragma unroll 2
        for (int cc = 0; cc < 16; ++cc) {
            const int c = wave * 16 + cc;
            float s0 = 0, s1 = 0, s2 = 0, s3 = 0;
            #pragma unroll
            for (int d4 = 0; d4 < 16; ++d4) {
                float4 kv = *(const float4*)&ks[c][d4 * 4];
                s0 = fmaf(qr[d4*4+0], kv.x, s0);
                s1 = fmaf(qr[d4*4+1], kv.y, s1);
                s2 = fmaf(qr[d4*4+2], kv.z, s2);
                s3 = fmaf(qr[d4*4+3], kv.w, s3);
            }
            const float s = (((s0 + s1) + (s2 + s3))) * SCALE;
            ps[c][lane] = __expf(s) * rl;
        }
        __syncthreads();
        #pragma unroll 4
        for (int c = 0; c < 64; ++c) {
            float4 p4 = *(const float4*)&ps[c][tq];
            float4 v4 = *(const float4*)&vs[c][td];
            float pv[4] = {p4.x, p4.y, p4.z, p4.w};
            float vv[4] = {v4.x, v4.y, v4.z, v4.w};
            #pragma unroll
            for (int i = 0; i < 4; ++i)
                #pragma unroll
                for (int j = 0; j < 4; ++j)
                    acc[i][j] = fmaf(pv[i], vv[j], acc[i][j]);
        }
    }
    #pragma unroll
    for (int i = 0; i < 4; ++i) {
        float4 val;
        val.x = acc[i][0]; val.y = acc[i][1]; val.z = acc[i][2]; val.w = acc[i][3];
        *(float4*)(opiv + ((size_t)(b * KPIV + r0 + tq + i)) * CC + h * DD + td) = val;
    }
}

// ---------------- K7: output projection of pivot rows -> fp32 out -----------
__global__ __launch_bounds__(256) void proj_k(
    const float* __restrict__ opiv, const float* __restrict__ wp,
    const float* __restrict__ bp, float* __restrict__ out)
{
    __shared__ __attribute__((aligned(16))) float os[8][CC];
    const int t = threadIdx.x;
    const int r0 = blockIdx.x * 8;
    for (int f = t; f < 1024; f += 256) {
        const int rr = f >> 7, i = (f & 127) * 4;
        *(float4*)&os[rr][i] = *(const float4*)(opiv + (size_t)(r0 + rr) * CC + i);
    }
    __syncthreads();
    const int c0 = t;
    float acc0[8] = {}, acc1[8] = {};
    for (int i = 0; i < CC; ++i) {
        const float w0 = wp[(size_t)i * CC + c0];
        const float w1 = wp[(size_t)i * CC + c0 + 256];
        #pragma unroll
        for (int rr = 0; rr < 8; ++rr) {
            const float ov = os[rr][i];
            acc0[rr] = fmaf(ov, w0, acc0[rr]);
            acc1[rr] = fmaf(ov, w1, acc1[rr]);
        }
    }
    const float b0 = bp[c0], b1 = bp[c0 + 256];
    #pragma unroll
    for (int rr = 0; rr < 8; ++rr) {
        out[((size_t)(r0 + rr)) * CC + c0]       = acc0[rr] + b0;
        out[((size_t)(r0 + rr)) * CC + c0 + 256] = acc1[rr] + b1;
    }
}

extern "C" void kernel_launch(void* const* d_in, const int* in_sizes, int n_in,
                              void* d_out, int out_size, void* d_ws, size_t ws_size,
                              hipStream_t stream)
{
    const float* x     = (const float*)d_in[0];
    const float* wqkv  = (const float*)d_in[1];
    const float* wproj = (const float*)d_in[2];
    const float* bproj = (const float*)d_in[3];

    // workspace layout: ~52.8 MB total (q/k fp32, v bf16, l fp32, imp fp64)
    float*    q      = (float*)d_ws;                                  // 16.78 MB
    float*    k      = q + (size_t)BB * HH * NN * DD;                 // 16.78 MB
    ushort_t* v      = (ushort_t*)(k + (size_t)BB * HH * NN * DD);    //  8.39 MB
    float*    l      = (float*)(v + (size_t)BB * HH * NN * DD);       //  0.26 MB
    float*    colsum = l + (size_t)BB * HH * NN;                      //  8.39 MB
    double*   imp    = (double*)(colsum + (size_t)512 * NN);          //  0.07 MB
    int*      idx    = (int*)(imp + BB * NN);                         //  4 KB
    float*    opiv   = (float*)(idx + BB * KPIV);                     //  2.10 MB
    float*    out    = (float*)d_out;

    const size_t need = (size_t)((char*)(opiv + (size_t)BB * KPIV * CC) - (char*)d_ws);
    if (ws_size < need) return;   // signature: out stays 0 -> absmax ~0.254

    qkv_gemm_k<<<dim3(64, 12), 256, 0, stream>>>(x, wqkv, q, k, v);
    pass_a_k<<<512, 256, 0, stream>>>(q, k, l);
    pass_b_k<<<512, 256, 0, stream>>>(q, k, l, colsum);
    imp_reduce_k<<<32, 256, 0, stream>>>(colsum, imp);
    topk_k<<<2, 1024, 0, stream>>>(imp, idx);
    pass_c_k<<<128, 256, 0, stream>>>(q, k, v, l, idx, opiv);
    proj_k<<<128, 256, 0, stream>>>(opiv, wproj, bproj, out);
}

// Round 7
// 794.896 us; speedup vs baseline: 2.8304x; 1.5094x over previous
//
#include <hip/hip_runtime.h>
#include <hip/hip_bf16.h>

#define BB 2
#define NN 4096
#define CC 512
#define HH 8
#define DD 64
#define KPIV 512
#define SCALE 0.125f

typedef unsigned short ushort_t;
typedef __attribute__((ext_vector_type(8))) short short8;
typedef __attribute__((ext_vector_type(16))) float float16;

__device__ __forceinline__ float bf2f(ushort_t h) {
    union { unsigned u; float f; } x; x.u = ((unsigned)h) << 16; return x.f;
}
__device__ __forceinline__ ushort_t f2bf(float f) {
    __hip_bfloat16 h = __float2bfloat16(f);
    ushort_t u;
    __builtin_memcpy(&u, &h, sizeof(u));
    return u;
}
// 3-term bf16 decomposition: x ~= a+b+c to ~24 mantissa bits
__device__ __forceinline__ void split3(float x, short& a, short& b, short& c) {
    const ushort_t h1 = f2bf(x);
    const float r1 = x - bf2f(h1);
    const ushort_t h2 = f2bf(r1);
    const float r2 = r1 - bf2f(h2);
    const ushort_t h3 = f2bf(r2);
    a = (short)h1; b = (short)h2; c = (short)h3;
}

// ---------------- K1: QKV projection GEMM, 128x128 tile, 8x8 reg blocking ---
// x: [B*N, C] fp32, w: [C, 3C] fp32 -> q,k fp32 [B,H,N,D], v bf16 TRANSPOSED [B,H,D,N]
__global__ __launch_bounds__(256) void qkv_gemm_k(
    const float* __restrict__ x, const float* __restrict__ w,
    float* __restrict__ q, float* __restrict__ k, ushort_t* __restrict__ v)
{
    __shared__ __attribute__((aligned(16))) float xs[16][132];  // [kk][m]
    __shared__ __attribute__((aligned(16))) float ws[16][132];  // [kk][n]
    const int t = threadIdx.x;
    const int row0 = blockIdx.x * 128;
    const int col0 = blockIdx.y * 128;
    const int tr = t & 15, tc = t >> 4;
    const int ts = col0 >> 9;   // tensor select, constant per block
    float acc[8][8] = {};
    for (int k0 = 0; k0 < CC; k0 += 16) {
        __syncthreads();
        {   // stage x tile 128 rows x 16 k, transposed
            const int r = t >> 1, off = (t & 1) * 8;
            const float* xp = x + (size_t)(row0 + r) * CC + k0 + off;
            float4 v0 = *(const float4*)xp;
            float4 v1 = *(const float4*)(xp + 4);
            xs[off + 0][r] = v0.x; xs[off + 1][r] = v0.y;
            xs[off + 2][r] = v0.z; xs[off + 3][r] = v0.w;
            xs[off + 4][r] = v1.x; xs[off + 5][r] = v1.y;
            xs[off + 6][r] = v1.z; xs[off + 7][r] = v1.w;
        }
        {   // stage w tile 16 k x 128 cols
            const int kk = t >> 4, c8 = (t & 15) * 8;
            const float* wp2 = w + (size_t)(k0 + kk) * (3 * CC) + col0 + c8;
            *(float4*)&ws[kk][c8]     = *(const float4*)wp2;
            *(float4*)&ws[kk][c8 + 4] = *(const float4*)(wp2 + 4);
        }
        __syncthreads();
        #pragma unroll
        for (int kk = 0; kk < 16; ++kk) {
            float a[8], b[8];
            *(float4*)&a[0] = *(const float4*)&xs[kk][tr * 8];
            *(float4*)&a[4] = *(const float4*)&xs[kk][tr * 8 + 4];
            *(float4*)&b[0] = *(const float4*)&ws[kk][tc * 8];
            *(float4*)&b[4] = *(const float4*)&ws[kk][tc * 8 + 4];
            #pragma unroll
            for (int i = 0; i < 8; ++i)
                #pragma unroll
                for (int j = 0; j < 8; ++j)
                    acc[i][j] = fmaf(a[i], b[j], acc[i][j]);
        }
    }
    const int gc0 = col0 + tc * 8;
    const int hh = (gc0 >> 6) & 7;
    const int dd0 = gc0 & 63;                 // 8-col group within one head
    #pragma unroll
    for (int i = 0; i < 8; ++i) {
        const int grow = row0 + tr * 8 + i;
        const int b = grow >> 12, n = grow & (NN - 1);
        if (ts < 2) {
            float* dst = ts ? k : q;
            const size_t base = (((size_t)b * HH + hh) * NN + n) * DD + dd0;
            float4 v0, v1;
            v0.x = acc[i][0]; v0.y = acc[i][1]; v0.z = acc[i][2]; v0.w = acc[i][3];
            v1.x = acc[i][4]; v1.y = acc[i][5]; v1.z = acc[i][6]; v1.w = acc[i][7];
            *(float4*)(dst + base) = v0;
            *(float4*)(dst + base + 4) = v1;
        } else {
            // transposed v: [b,h,d,n] bf16 (scalar stores; one-time epilogue)
            #pragma unroll
            for (int j = 0; j < 8; ++j)
                v[(((size_t)b * HH + hh) * DD + dd0 + j) * NN + n] = f2bf(acc[i][j]);
        }
    }
}

// ---------------- shared MFMA S-pass machinery (3x3 split, 6 MFMAs) ---------
// MFMA 32x32x16 layouts: A[m=lane&31][kd=(lane>>5)*8+j], B[k][n=lane&31],
// C: col=lane&31, row=(reg&3)+8*(reg>>2)+4*(lane>>5)

__device__ __forceinline__ void load_q_frags3(
    const float* __restrict__ q, int bh, int qt, int wv, int ln, int g,
    short8* q1, short8* q2, short8* q3)
{
    const float* qp = q + ((size_t)bh * NN + qt * 128 + wv * 32 + ln) * DD + g * 8;
    #pragma unroll
    for (int c = 0; c < 4; ++c) {
        float4 f0 = *(const float4*)(qp + c * 16);
        float4 f1 = *(const float4*)(qp + c * 16 + 4);
        float xv[8] = {f0.x, f0.y, f0.z, f0.w, f1.x, f1.y, f1.z, f1.w};
        #pragma unroll
        for (int j = 0; j < 8; ++j) {
            short a, b, cc2;
            split3(xv[j] * SCALE, a, b, cc2);   // *0.125 exact (pow2)
            q1[c][j] = a; q2[c][j] = b; q3[c][j] = cc2;
        }
    }
}

__device__ __forceinline__ void stage_k_tile3(
    const float* __restrict__ k, int bh, int n0, int t,
    short8* k1, short8* k2, short8* k3)
{
    const int tok = t & 31, seg = t >> 5;     // d range = seg*8..seg*8+8
    const float* kp = k + ((size_t)bh * NN + n0 + tok) * DD + seg * 8;
    float4 f0 = *(const float4*)kp;
    float4 f1 = *(const float4*)(kp + 4);
    float xv[8] = {f0.x, f0.y, f0.z, f0.w, f1.x, f1.y, f1.z, f1.w};
    short8 h1, h2, h3;
    #pragma unroll
    for (int j = 0; j < 8; ++j) {
        short a, b, c;
        split3(xv[j], a, b, c);
        h1[j] = a; h2[j] = b; h3[j] = c;
    }
    k1[seg * 32 + tok] = h1;
    k2[seg * 32 + tok] = h2;
    k3[seg * 32 + tok] = h3;
}

#define SIX_MFMA(c)                                                        \
    {                                                                      \
        short8 b1 = k1s[((c) * 2 + g) * 32 + ln];                          \
        short8 b2 = k2s[((c) * 2 + g) * 32 + ln];                          \
        short8 b3 = k3s[((c) * 2 + g) * 32 + ln];                          \
        a0  = __builtin_amdgcn_mfma_f32_32x32x16_bf16(q1[c], b1, a0, 0,0,0); \
        ar1 = __builtin_amdgcn_mfma_f32_32x32x16_bf16(q2[c], b1, ar1,0,0,0); \
        ar1 = __builtin_amdgcn_mfma_f32_32x32x16_bf16(q1[c], b2, ar1,0,0,0); \
        ar2 = __builtin_amdgcn_mfma_f32_32x32x16_bf16(q2[c], b2, ar2,0,0,0); \
        ar2 = __builtin_amdgcn_mfma_f32_32x32x16_bf16(q3[c], b1, ar2,0,0,0); \
        ar1 = __builtin_amdgcn_mfma_f32_32x32x16_bf16(q1[c], b3, ar1,0,0,0); \
    }

// ---------------- K2: pass A — per-row softmax denominator l ----------------
__global__ __launch_bounds__(256) void pass_a_k(
    const float* __restrict__ q, const float* __restrict__ k,
    float* __restrict__ l)
{
    __shared__ short8 k1s[8 * 32];
    __shared__ short8 k2s[8 * 32];
    __shared__ short8 k3s[8 * 32];
    const int t = threadIdx.x;
    const int lane = t & 63, wv = t >> 6;
    const int g = lane >> 5, ln = lane & 31;
    const int bh = blockIdx.x >> 5;
    const int qt = blockIdx.x & 31;
    short8 q1[4], q2[4], q3[4];
    load_q_frags3(q, bh, qt, wv, ln, g, q1, q2, q3);
    float rowacc[16];
    #pragma unroll
    for (int r = 0; r < 16; ++r) rowacc[r] = 0.f;
    for (int n0 = 0; n0 < NN; n0 += 32) {
        __syncthreads();
        stage_k_tile3(k, bh, n0, t, k1s, k2s, k3s);
        __syncthreads();
        float16 a0, ar1, ar2;
        #pragma unroll
        for (int i = 0; i < 16; ++i) { a0[i] = 0.f; ar1[i] = 0.f; ar2[i] = 0.f; }
        SIX_MFMA(0) SIX_MFMA(1) SIX_MFMA(2) SIX_MFMA(3)
        #pragma unroll
        for (int r = 0; r < 16; ++r)
            rowacc[r] += __expf(a0[r] + (ar1[r] + ar2[r]));
    }
    #pragma unroll
    for (int r = 0; r < 16; ++r) {
        float vs = rowacc[r];
        vs += __shfl_xor(vs, 1);
        vs += __shfl_xor(vs, 2);
        vs += __shfl_xor(vs, 4);
        vs += __shfl_xor(vs, 8);
        vs += __shfl_xor(vs, 16);
        rowacc[r] = vs;
    }
    if (ln == 0) {
        #pragma unroll
        for (int r = 0; r < 16; ++r) {
            const int row = (r & 3) + 8 * (r >> 2) + 4 * g;
            l[(size_t)bh * NN + qt * 128 + wv * 32 + row] = rowacc[r];
        }
    }
}

// ---------------- K3: pass B — column sums of P -> colsum[512][4096] --------
__global__ __launch_bounds__(256) void pass_b_k(
    const float* __restrict__ q, const float* __restrict__ k,
    const float* __restrict__ l, float* __restrict__ colsum)
{
    __shared__ short8 k1s[8 * 32];
    __shared__ short8 k2s[8 * 32];
    __shared__ short8 k3s[8 * 32];
    __shared__ float csbuf[4][32];
    const int t = threadIdx.x;
    const int lane = t & 63, wv = t >> 6;
    const int g = lane >> 5, ln = lane & 31;
    const int bh = blockIdx.x >> 5;
    const int qt = blockIdx.x & 31;
    short8 q1[4], q2[4], q3[4];
    load_q_frags3(q, bh, qt, wv, ln, g, q1, q2, q3);
    float rv[16];
    #pragma unroll
    for (int r = 0; r < 16; ++r) {
        const int row = (r & 3) + 8 * (r >> 2) + 4 * g;
        rv[r] = 1.0f / l[(size_t)bh * NN + qt * 128 + wv * 32 + row];
    }
    for (int n0 = 0; n0 < NN; n0 += 32) {
        __syncthreads();
        stage_k_tile3(k, bh, n0, t, k1s, k2s, k3s);
        if (n0 > 0 && t < 32)
            colsum[(size_t)blockIdx.x * NN + (n0 - 32) + t] =
                (csbuf[0][t] + csbuf[1][t]) + (csbuf[2][t] + csbuf[3][t]);
        __syncthreads();
        float16 a0, ar1, ar2;
        #pragma unroll
        for (int i = 0; i < 16; ++i) { a0[i] = 0.f; ar1[i] = 0.f; ar2[i] = 0.f; }
        SIX_MFMA(0) SIX_MFMA(1) SIX_MFMA(2) SIX_MFMA(3)
        float cs = 0.f;
        #pragma unroll
        for (int r = 0; r < 16; ++r)
            cs = fmaf(__expf(a0[r] + (ar1[r] + ar2[r])), rv[r], cs);
        cs += __shfl_xor(cs, 32);
        if (g == 0) csbuf[wv][ln] = cs;
    }
    __syncthreads();
    if (t < 32)
        colsum[(size_t)blockIdx.x * NN + (NN - 32) + t] =
            (csbuf[0][t] + csbuf[1][t]) + (csbuf[2][t] + csbuf[3][t]);
}

// ---------------- K4: reduce partials -> importance (fp64) ------------------
__global__ __launch_bounds__(256) void imp_reduce_k(
    const float* __restrict__ colsum, double* __restrict__ imp)
{
    const int n = blockIdx.x * 256 + threadIdx.x;   // 0..8191
    const int b = n >> 12, c = n & (NN - 1);
    const float* p = colsum + (size_t)b * 256 * NN + c;
    double s = 0.0;
    for (int i = 0; i < 256; ++i) s += (double)p[(size_t)i * NN];
    imp[n] = s * (1.0 / (double)(HH * NN));
}

// ---------------- K5: exact top-K via full bitonic sort on fp64 keys --------
__global__ __launch_bounds__(1024) void topk_k(
    const double* __restrict__ imp, int* __restrict__ idxout)
{
    __shared__ double sv[4096];
    __shared__ int si[4096];
    const int b = blockIdx.x, t = threadIdx.x;
    for (int i = t; i < 4096; i += 1024) { sv[i] = imp[b * 4096 + i]; si[i] = i; }
    __syncthreads();
    for (int kk = 2; kk <= 4096; kk <<= 1) {
        for (int j = kk >> 1; j > 0; j >>= 1) {
            #pragma unroll 1
            for (int r = 0; r < 2; ++r) {
                const int cm = t + r * 1024;
                const int i = ((cm & ~(j - 1)) << 1) | (cm & (j - 1));
                const int lo = i | j;
                const bool up = ((i & kk) == 0);
                const double va = sv[i], vb = sv[lo];
                const int ia = si[i], ib = si[lo];
                const bool after = (va < vb) || (va == vb && ia > ib);
                if (after == up) { sv[i] = vb; sv[lo] = va; si[i] = ib; si[lo] = ia; }
            }
            __syncthreads();
        }
    }
    if (t < KPIV) idxout[b * KPIV + t] = si[t];
}

// ---------------- K6: O = P@V for pivot rows, MFMA --------------------------
// grid 512 = b(2) x h(8) x chunk(16 of 32 pivots) x tokhalf(2); 4 waves split
// the 2048-token half into 512 each. S via 2-way split (3 MFMA / K=16 slice),
// P->bf16->wave-private LDS transpose (C-layout -> A-layout), PV via MFMA with
// V read d-major (transposed) as contiguous uint4 B-frags. Partial O combined
// across blocks by atomicAdd into zeroed opiv (value path: nondet rounding ok).
__global__ __launch_bounds__(256) void pass_c_k(
    const float* __restrict__ q, const float* __restrict__ k,
    const ushort_t* __restrict__ vt, const float* __restrict__ l,
    const int* __restrict__ idx, float* __restrict__ opiv)
{
    __shared__ short8 pfr[4][4][32];                            // [wv][kh*2+g][q]
    __shared__ __attribute__((aligned(16))) float osum[4][32][64];
    const int t = threadIdx.x;
    const int lane = t & 63, wv = t >> 6;
    const int g = lane >> 5, ln = lane & 31;
    const int bid = blockIdx.x;
    const int b = bid >> 8, h = (bid >> 5) & 7;
    const int chunk = (bid >> 1) & 15, th = bid & 1;
    const int bh = b * HH + h;
    const int r0 = chunk * 32;
    // A-frags: 32 pivot q-rows, hi/lo split, q prescaled by SCALE (exact)
    const int tokq = idx[b * KPIV + r0 + ln];
    short8 qh[4], qlo[4];
    {
        const float* qp = q + ((size_t)bh * NN + tokq) * DD + g * 8;
        #pragma unroll
        for (int kd = 0; kd < 4; ++kd) {
            float4 f0 = *(const float4*)(qp + kd * 16);
            float4 f1 = *(const float4*)(qp + kd * 16 + 4);
            float xv[8] = {f0.x, f0.y, f0.z, f0.w, f1.x, f1.y, f1.z, f1.w};
            #pragma unroll
            for (int j = 0; j < 8; ++j) {
                const float sv = xv[j] * SCALE;
                const ushort_t hi = f2bf(sv);
                qh[kd][j]  = (short)hi;
                qlo[kd][j] = (short)f2bf(sv - bf2f(hi));
            }
        }
    }
    float rv[16];
    #pragma unroll
    for (int r = 0; r < 16; ++r) {
        const int row = (r & 3) + 8 * (r >> 2) + 4 * g;
        rv[r] = 1.0f / l[(size_t)bh * NN + idx[b * KPIV + r0 + row]];
    }
    float16 oacc0, oacc1;
    #pragma unroll
    for (int i = 0; i < 16; ++i) { oacc0[i] = 0.f; oacc1[i] = 0.f; }
    const int base_n = th * 2048 + wv * 512;
    for (int step = 0; step < 16; ++step) {
        const int n0 = base_n + step * 32;
        float16 shh, sx;
        #pragma unroll
        for (int i = 0; i < 16; ++i) { shh[i] = 0.f; sx[i] = 0.f; }
        // K B-frags direct from global (8 contiguous d of token n0+ln) + split
        const float* kp = k + ((size_t)bh * NN + n0 + ln) * DD + g * 8;
        #pragma unroll
        for (int kd = 0; kd < 4; ++kd) {
            float4 f0 = *(const float4*)(kp + kd * 16);
            float4 f1 = *(const float4*)(kp + kd * 16 + 4);
            float xv[8] = {f0.x, f0.y, f0.z, f0.w, f1.x, f1.y, f1.z, f1.w};
            short8 bh8, bl8;
            #pragma unroll
            for (int j = 0; j < 8; ++j) {
                const ushort_t hi = f2bf(xv[j]);
                bh8[j] = (short)hi;
                bl8[j] = (short)f2bf(xv[j] - bf2f(hi));
            }
            shh = __builtin_amdgcn_mfma_f32_32x32x16_bf16(qh[kd],  bh8, shh, 0,0,0);
            sx  = __builtin_amdgcn_mfma_f32_32x32x16_bf16(qlo[kd], bh8, sx,  0,0,0);
            sx  = __builtin_amdgcn_mfma_f32_32x32x16_bf16(qh[kd],  bl8, sx,  0,0,0);
        }
        __syncthreads();   // pfr(prev step) reads complete everywhere
        // P = exp(s)/l -> bf16 -> LDS transpose: element (row, tok=ln) ->
        // pfr[wv][ln>>3][row] slot (ln&7)
        #pragma unroll
        for (int r = 0; r < 16; ++r) {
            const int row = (r & 3) + 8 * (r >> 2) + 4 * g;
            const float p = __expf(shh[r] + sx[r]) * rv[r];
            *((ushort_t*)&pfr[wv][ln >> 3][row] + (ln & 7)) = f2bf(p);
        }
        __syncthreads();   // P visible
        // PV: A = P (A-layout from pfr), B = V d-major contiguous uint4
        #pragma unroll
        for (int kh = 0; kh < 2; ++kh) {
            short8 pa = pfr[wv][kh * 2 + g][ln];
            const ushort_t* vp0 = vt + ((size_t)bh * DD + ln) * NN + n0 + kh * 16 + g * 8;
            uint4 u0 = *(const uint4*)vp0;
            uint4 u1 = *(const uint4*)(vp0 + (size_t)32 * NN);
            short8 vb0, vb1;
            __builtin_memcpy(&vb0, &u0, 16);
            __builtin_memcpy(&vb1, &u1, 16);
            oacc0 = __builtin_amdgcn_mfma_f32_32x32x16_bf16(pa, vb0, oacc0, 0,0,0);
            oacc1 = __builtin_amdgcn_mfma_f32_32x32x16_bf16(pa, vb1, oacc1, 0,0,0);
        }
    }
    // cross-wave reduce + atomic combine across token-half blocks
    #pragma unroll
    for (int r = 0; r < 16; ++r) {
        const int row = (r & 3) + 8 * (r >> 2) + 4 * g;
        osum[wv][row][ln]      = oacc0[r];
        osum[wv][row][32 + ln] = oacc1[r];
    }
    __syncthreads();
    {
        const int qrow = t >> 3, d0 = (t & 7) * 8;
        float s[8] = {};
        #pragma unroll
        for (int w = 0; w < 4; ++w) {
            float4 a  = *(const float4*)&osum[w][qrow][d0];
            float4 b2 = *(const float4*)&osum[w][qrow][d0 + 4];
            s[0] += a.x;  s[1] += a.y;  s[2] += a.z;  s[3] += a.w;
            s[4] += b2.x; s[5] += b2.y; s[6] += b2.z; s[7] += b2.w;
        }
        float* op = opiv + ((size_t)(b * KPIV + r0 + qrow)) * CC + h * DD + d0;
        #pragma unroll
        for (int j = 0; j < 8; ++j) atomicAdd(op + j, s[j]);
    }
}

// ---------------- K7: output projection of pivot rows -> fp32 out -----------
__global__ __launch_bounds__(256) void proj_k(
    const float* __restrict__ opiv, const float* __restrict__ wp,
    const float* __restrict__ bp, float* __restrict__ out)
{
    __shared__ __attribute__((aligned(16))) float os[8][CC];
    const int t = threadIdx.x;
    const int r0 = blockIdx.x * 8;
    for (int f = t; f < 1024; f += 256) {
        const int rr = f >> 7, i = (f & 127) * 4;
        *(float4*)&os[rr][i] = *(const float4*)(opiv + (size_t)(r0 + rr) * CC + i);
    }
    __syncthreads();
    const int c0 = t;
    float acc0[8] = {}, acc1[8] = {};
    for (int i = 0; i < CC; ++i) {
        const float w0 = wp[(size_t)i * CC + c0];
        const float w1 = wp[(size_t)i * CC + c0 + 256];
        #pragma unroll
        for (int rr = 0; rr < 8; ++rr) {
            const float ov = os[rr][i];
            acc0[rr] = fmaf(ov, w0, acc0[rr]);
            acc1[rr] = fmaf(ov, w1, acc1[rr]);
        }
    }
    const float b0 = bp[c0], b1 = bp[c0 + 256];
    #pragma unroll
    for (int rr = 0; rr < 8; ++rr) {
        out[((size_t)(r0 + rr)) * CC + c0]       = acc0[rr] + b0;
        out[((size_t)(r0 + rr)) * CC + c0 + 256] = acc1[rr] + b1;
    }
}

extern "C" void kernel_launch(void* const* d_in, const int* in_sizes, int n_in,
                              void* d_out, int out_size, void* d_ws, size_t ws_size,
                              hipStream_t stream)
{
    const float* x     = (const float*)d_in[0];
    const float* wqkv  = (const float*)d_in[1];
    const float* wproj = (const float*)d_in[2];
    const float* bproj = (const float*)d_in[3];

    // workspace layout: ~52.8 MB total
    float*    q      = (float*)d_ws;                                  // 16.78 MB
    float*    k      = q + (size_t)BB * HH * NN * DD;                 // 16.78 MB
    ushort_t* v      = (ushort_t*)(k + (size_t)BB * HH * NN * DD);    //  8.39 MB (d-major)
    float*    l      = (float*)(v + (size_t)BB * HH * NN * DD);       //  0.26 MB
    float*    colsum = l + (size_t)BB * HH * NN;                      //  8.39 MB
    double*   imp    = (double*)(colsum + (size_t)512 * NN);          //  0.07 MB
    int*      idx    = (int*)(imp + BB * NN);                         //  4 KB
    float*    opiv   = (float*)(idx + BB * KPIV);                     //  2.10 MB
    float*    out    = (float*)d_out;

    const size_t need = (size_t)((char*)(opiv + (size_t)BB * KPIV * CC) - (char*)d_ws);
    if (ws_size < need) return;   // signature: out stays 0 -> absmax ~0.254

    qkv_gemm_k<<<dim3(64, 12), 256, 0, stream>>>(x, wqkv, q, k, v);
    pass_a_k<<<512, 256, 0, stream>>>(q, k, l);
    pass_b_k<<<512, 256, 0, stream>>>(q, k, l, colsum);
    imp_reduce_k<<<32, 256, 0, stream>>>(colsum, imp);
    topk_k<<<2, 1024, 0, stream>>>(imp, idx);
    hipMemsetAsync(opiv, 0, (size_t)BB * KPIV * CC * sizeof(float), stream);
    pass_c_k<<<512, 256, 0, stream>>>(q, k, v, l, idx, opiv);
    proj_k<<<128, 256, 0, stream>>>(opiv, wproj, bproj, out);
}

// Round 8
// 689.394 us; speedup vs baseline: 3.2635x; 1.1530x over previous
//
#include <hip/hip_runtime.h>
#include <hip/hip_bf16.h>

#define BB 2
#define NN 4096
#define CC 512
#define HH 8
#define DD 64
#define KPIV 512
#define SCALE 0.125f
#define C2INV 4.8828125e-4f   /* 2^-11 */
#define C2    2048.0f         /* 2^11  */

typedef unsigned short ushort_t;
typedef __attribute__((ext_vector_type(8))) short short8;
typedef __attribute__((ext_vector_type(8))) _Float16 half8;
typedef __attribute__((ext_vector_type(16))) float float16;

__device__ __forceinline__ float bf2f(ushort_t h) {
    union { unsigned u; float f; } x; x.u = ((unsigned)h) << 16; return x.f;
}
__device__ __forceinline__ ushort_t f2bf(float f) {
    __hip_bfloat16 h = __float2bfloat16(f);
    ushort_t u;
    __builtin_memcpy(&u, &h, sizeof(u));
    return u;
}
// fp32 ~= hi + 2^-11 * lo, both f16, lo prescaled into normal range
__device__ __forceinline__ void split2h(float x, _Float16& hi, _Float16& lo) {
    hi = (_Float16)x;
    lo = (_Float16)((x - (float)hi) * C2);
}

// ---------------- K1: QKV projection GEMM, 128x128 tile, 8x8 reg blocking ---
// x,w fp32 -> q fp32 [B,H,N,D], k as (kh,kl) f16 [B,H,N,D], v bf16 [B,H,D,N]
__global__ __launch_bounds__(256) void qkv_gemm_k(
    const float* __restrict__ x, const float* __restrict__ w,
    float* __restrict__ q, _Float16* __restrict__ khg, _Float16* __restrict__ klg,
    ushort_t* __restrict__ v)
{
    __shared__ __attribute__((aligned(16))) float xs[16][132];  // [kk][m]
    __shared__ __attribute__((aligned(16))) float ws[16][132];  // [kk][n]
    const int t = threadIdx.x;
    const int row0 = blockIdx.x * 128;
    const int col0 = blockIdx.y * 128;
    const int tr = t & 15, tc = t >> 4;
    const int ts = col0 >> 9;   // tensor select, constant per block
    float acc[8][8] = {};
    for (int k0 = 0; k0 < CC; k0 += 16) {
        __syncthreads();
        {   // stage x tile 128 rows x 16 k, transposed
            const int r = t >> 1, off = (t & 1) * 8;
            const float* xp = x + (size_t)(row0 + r) * CC + k0 + off;
            float4 v0 = *(const float4*)xp;
            float4 v1 = *(const float4*)(xp + 4);
            xs[off + 0][r] = v0.x; xs[off + 1][r] = v0.y;
            xs[off + 2][r] = v0.z; xs[off + 3][r] = v0.w;
            xs[off + 4][r] = v1.x; xs[off + 5][r] = v1.y;
            xs[off + 6][r] = v1.z; xs[off + 7][r] = v1.w;
        }
        {   // stage w tile 16 k x 128 cols
            const int kk = t >> 4, c8 = (t & 15) * 8;
            const float* wp2 = w + (size_t)(k0 + kk) * (3 * CC) + col0 + c8;
            *(float4*)&ws[kk][c8]     = *(const float4*)wp2;
            *(float4*)&ws[kk][c8 + 4] = *(const float4*)(wp2 + 4);
        }
        __syncthreads();
        #pragma unroll
        for (int kk = 0; kk < 16; ++kk) {
            float a[8], b[8];
            *(float4*)&a[0] = *(const float4*)&xs[kk][tr * 8];
            *(float4*)&a[4] = *(const float4*)&xs[kk][tr * 8 + 4];
            *(float4*)&b[0] = *(const float4*)&ws[kk][tc * 8];
            *(float4*)&b[4] = *(const float4*)&ws[kk][tc * 8 + 4];
            #pragma unroll
            for (int i = 0; i < 8; ++i)
                #pragma unroll
                for (int j = 0; j < 8; ++j)
                    acc[i][j] = fmaf(a[i], b[j], acc[i][j]);
        }
    }
    const int gc0 = col0 + tc * 8;
    const int hh = (gc0 >> 6) & 7;
    const int dd0 = gc0 & 63;                 // 8-col group within one head
    #pragma unroll
    for (int i = 0; i < 8; ++i) {
        const int grow = row0 + tr * 8 + i;
        const int b = grow >> 12, n = grow & (NN - 1);
        const size_t base = (((size_t)b * HH + hh) * NN + n) * DD + dd0;
        if (ts == 0) {
            float4 v0, v1;
            v0.x = acc[i][0]; v0.y = acc[i][1]; v0.z = acc[i][2]; v0.w = acc[i][3];
            v1.x = acc[i][4]; v1.y = acc[i][5]; v1.z = acc[i][6]; v1.w = acc[i][7];
            *(float4*)(q + base) = v0;
            *(float4*)(q + base + 4) = v1;
        } else if (ts == 1) {
            half8 h8, l8;
            #pragma unroll
            for (int j = 0; j < 8; ++j) {
                _Float16 a2, b2; split2h(acc[i][j], a2, b2);
                h8[j] = a2; l8[j] = b2;
            }
            *(half8*)(khg + base) = h8;
            *(half8*)(klg + base) = l8;
        } else {
            // transposed v: [b,h,d,n] bf16 (scalar stores; one-time epilogue)
            #pragma unroll
            for (int j = 0; j < 8; ++j)
                v[(((size_t)b * HH + hh) * DD + dd0 + j) * NN + n] = f2bf(acc[i][j]);
        }
    }
}

// ---------------- shared f16 MFMA S-pass machinery --------------------------
// MFMA 32x32x16 layouts: A[m=lane&31][kd=(lane>>5)*8+j], B[k][n=lane&31],
// C: col=lane&31, row=(reg&3)+8*(reg>>2)+4*(lane>>5)
// s = a0(qh.kh) + 2^-11 * a12(ql.kh + qh.kl)

__device__ __forceinline__ void load_q_frags_h(
    const float* __restrict__ q, size_t row, int g, half8* qh, half8* ql)
{
    const float* qp = q + row * DD + g * 8;
    #pragma unroll
    for (int kd = 0; kd < 4; ++kd) {
        float4 f0 = *(const float4*)(qp + kd * 16);
        float4 f1 = *(const float4*)(qp + kd * 16 + 4);
        float xv[8] = {f0.x, f0.y, f0.z, f0.w, f1.x, f1.y, f1.z, f1.w};
        #pragma unroll
        for (int j = 0; j < 8; ++j) {
            _Float16 a2, b2; split2h(xv[j] * SCALE, a2, b2);  // *0.125 exact
            qh[kd][j] = a2; ql[kd][j] = b2;
        }
    }
}

// stage 128 tokens (kh+kl) into LDS: pure copy, no repack
__device__ __forceinline__ void stage_k128(
    const _Float16* __restrict__ khg, const _Float16* __restrict__ klg,
    int bh, int n0, int t, half8* khs, half8* kls)
{
    const _Float16* kb = khg + ((size_t)bh * NN + n0) * DD;
    const _Float16* lb = klg + ((size_t)bh * NN + n0) * DD;
    #pragma unroll
    for (int j = 0; j < 4; ++j) {
        const int s = t + j * 256;
        const int seg = s >> 7, tok = s & 127;
        const size_t off = (size_t)tok * DD + seg * 8;
        uint4 uh = *(const uint4*)(kb + off);
        uint4 ul = *(const uint4*)(lb + off);
        *(uint4*)&khs[seg * 128 + tok] = uh;
        *(uint4*)&kls[seg * 128 + tok] = ul;
    }
}

#define S_MFMA_STEP(t0)                                                       \
    float16 a0, a12;                                                          \
    _Pragma("unroll")                                                         \
    for (int i = 0; i < 16; ++i) { a0[i] = 0.f; a12[i] = 0.f; }               \
    _Pragma("unroll")                                                         \
    for (int kd = 0; kd < 4; ++kd) {                                          \
        half8 bhi = khs[(kd * 2 + g) * 128 + (t0) + ln];                      \
        half8 blo = kls[(kd * 2 + g) * 128 + (t0) + ln];                      \
        a0  = __builtin_amdgcn_mfma_f32_32x32x16_f16(qh[kd], bhi, a0, 0,0,0); \
        a12 = __builtin_amdgcn_mfma_f32_32x32x16_f16(ql[kd], bhi, a12,0,0,0); \
        a12 = __builtin_amdgcn_mfma_f32_32x32x16_f16(qh[kd], blo, a12,0,0,0); \
    }

// ---------------- K2: pass A — per-row softmax denominator l ----------------
__global__ __launch_bounds__(256) void pass_a_k(
    const float* __restrict__ q, const _Float16* __restrict__ khg,
    const _Float16* __restrict__ klg, float* __restrict__ l)
{
    __shared__ half8 khs[8 * 128];   // 16 KB
    __shared__ half8 kls[8 * 128];   // 16 KB
    const int t = threadIdx.x;
    const int lane = t & 63, wv = t >> 6;
    const int g = lane >> 5, ln = lane & 31;
    const int bh = blockIdx.x >> 5;
    const int qt = blockIdx.x & 31;
    half8 qh[4], ql[4];
    load_q_frags_h(q, (size_t)bh * NN + qt * 128 + wv * 32 + ln, g, qh, ql);
    float rowacc[16];
    #pragma unroll
    for (int r = 0; r < 16; ++r) rowacc[r] = 0.f;
    for (int n0 = 0; n0 < NN; n0 += 128) {
        __syncthreads();
        stage_k128(khg, klg, bh, n0, t, khs, kls);
        __syncthreads();
        #pragma unroll
        for (int ii = 0; ii < 4; ++ii) {
            S_MFMA_STEP(ii * 32)
            #pragma unroll
            for (int r = 0; r < 16; ++r)
                rowacc[r] += __expf(fmaf(a12[r], C2INV, a0[r]));
        }
    }
    #pragma unroll
    for (int r = 0; r < 16; ++r) {
        float vs = rowacc[r];
        vs += __shfl_xor(vs, 1);
        vs += __shfl_xor(vs, 2);
        vs += __shfl_xor(vs, 4);
        vs += __shfl_xor(vs, 8);
        vs += __shfl_xor(vs, 16);
        rowacc[r] = vs;
    }
    if (ln == 0) {
        #pragma unroll
        for (int r = 0; r < 16; ++r) {
            const int row = (r & 3) + 8 * (r >> 2) + 4 * g;
            l[(size_t)bh * NN + qt * 128 + wv * 32 + row] = rowacc[r];
        }
    }
}

// ---------------- K3: pass B — column sums of P -> colsum[512][4096] --------
__global__ __launch_bounds__(256) void pass_b_k(
    const float* __restrict__ q, const _Float16* __restrict__ khg,
    const _Float16* __restrict__ klg, const float* __restrict__ l,
    float* __restrict__ colsum)
{
    __shared__ half8 khs[8 * 128];
    __shared__ half8 kls[8 * 128];
    __shared__ float colbuf[4][128];
    const int t = threadIdx.x;
    const int lane = t & 63, wv = t >> 6;
    const int g = lane >> 5, ln = lane & 31;
    const int bh = blockIdx.x >> 5;
    const int qt = blockIdx.x & 31;
    half8 qh[4], ql[4];
    load_q_frags_h(q, (size_t)bh * NN + qt * 128 + wv * 32 + ln, g, qh, ql);
    float rv[16];
    #pragma unroll
    for (int r = 0; r < 16; ++r) {
        const int row = (r & 3) + 8 * (r >> 2) + 4 * g;
        rv[r] = 1.0f / l[(size_t)bh * NN + qt * 128 + wv * 32 + row];
    }
    for (int n0 = 0; n0 < NN; n0 += 128) {
        __syncthreads();   // prev inner reads + colbuf writes complete
        if (n0 > 0 && t < 128)   // drain previous superstep's column sums
            colsum[(size_t)blockIdx.x * NN + (n0 - 128) + t] =
                (colbuf[0][t] + colbuf[1][t]) + (colbuf[2][t] + colbuf[3][t]);
        stage_k128(khg, klg, bh, n0, t, khs, kls);
        __syncthreads();   // staging + drain complete
        #pragma unroll
        for (int ii = 0; ii < 4; ++ii) {
            S_MFMA_STEP(ii * 32)
            float cs = 0.f;
            #pragma unroll
            for (int r = 0; r < 16; ++r)
                cs = fmaf(__expf(fmaf(a12[r], C2INV, a0[r])), rv[r], cs);
            cs += __shfl_xor(cs, 32);   // other 16-row half, same column
            if (g == 0) colbuf[wv][ii * 32 + ln] = cs;
        }
    }
    __syncthreads();
    if (t < 128)
        colsum[(size_t)blockIdx.x * NN + (NN - 128) + t] =
            (colbuf[0][t] + colbuf[1][t]) + (colbuf[2][t] + colbuf[3][t]);
}

// ---------------- K4: reduce partials -> importance (fp64) ------------------
__global__ __launch_bounds__(256) void imp_reduce_k(
    const float* __restrict__ colsum, double* __restrict__ imp)
{
    const int n = blockIdx.x * 256 + threadIdx.x;   // 0..8191
    const int b = n >> 12, c = n & (NN - 1);
    const float* p = colsum + (size_t)b * 256 * NN + c;
    double s = 0.0;
    for (int i = 0; i < 256; ++i) s += (double)p[(size_t)i * NN];
    imp[n] = s * (1.0 / (double)(HH * NN));
}

// ---------------- K5: exact top-K via full bitonic sort on fp64 keys --------
__global__ __launch_bounds__(1024) void topk_k(
    const double* __restrict__ imp, int* __restrict__ idxout)
{
    __shared__ double sv[4096];
    __shared__ int si[4096];
    const int b = blockIdx.x, t = threadIdx.x;
    for (int i = t; i < 4096; i += 1024) { sv[i] = imp[b * 4096 + i]; si[i] = i; }
    __syncthreads();
    for (int kk = 2; kk <= 4096; kk <<= 1) {
        for (int j = kk >> 1; j > 0; j >>= 1) {
            #pragma unroll 1
            for (int r = 0; r < 2; ++r) {
                const int cm = t + r * 1024;
                const int i = ((cm & ~(j - 1)) << 1) | (cm & (j - 1));
                const int lo = i | j;
                const bool up = ((i & kk) == 0);
                const double va = sv[i], vb = sv[lo];
                const int ia = si[i], ib = si[lo];
                const bool after = (va < vb) || (va == vb && ia > ib);
                if (after == up) { sv[i] = vb; sv[lo] = va; si[i] = ib; si[lo] = ia; }
            }
            __syncthreads();
        }
    }
    if (t < KPIV) idxout[b * KPIV + t] = si[t];
}

// ---------------- K6: O = P@V for pivot rows, MFMA --------------------------
// grid 512 = b(2) x h(8) x chunk(16 of 32 pivots) x tokhalf(2); 4 waves split
// the 2048-token half into 512 each. S from (kh,kl) f16 pairs (3 MFMA/K16),
// P->bf16->wave-private LDS transpose, PV bf16 MFMA with V d-major.
// Partial O combined across blocks by atomicAdd into zeroed opiv (value path).
__global__ __launch_bounds__(256) void pass_c_k(
    const float* __restrict__ q, const _Float16* __restrict__ khg,
    const _Float16* __restrict__ klg, const ushort_t* __restrict__ vt,
    const float* __restrict__ l, const int* __restrict__ idx,
    float* __restrict__ opiv)
{
    __shared__ short8 pfr[4][4][32];                            // [wv][kh*2+g][q]
    __shared__ __attribute__((aligned(16))) float osum[4][32][64];
    const int t = threadIdx.x;
    const int lane = t & 63, wv = t >> 6;
    const int g = lane >> 5, ln = lane & 31;
    const int bid = blockIdx.x;
    const int b = bid >> 8, h = (bid >> 5) & 7;
    const int chunk = (bid >> 1) & 15, th = bid & 1;
    const int bh = b * HH + h;
    const int r0 = chunk * 32;
    const int tokq = idx[b * KPIV + r0 + ln];
    half8 qh[4], ql[4];
    load_q_frags_h(q, (size_t)bh * NN + tokq, g, qh, ql);
    float rv[16];
    #pragma unroll
    for (int r = 0; r < 16; ++r) {
        const int row = (r & 3) + 8 * (r >> 2) + 4 * g;
        rv[r] = 1.0f / l[(size_t)bh * NN + idx[b * KPIV + r0 + row]];
    }
    float16 oacc0, oacc1;
    #pragma unroll
    for (int i = 0; i < 16; ++i) { oacc0[i] = 0.f; oacc1[i] = 0.f; }
    const int base_n = th * 2048 + wv * 512;
    for (int step = 0; step < 16; ++step) {
        const int n0 = base_n + step * 32;
        float16 a0, a12;
        #pragma unroll
        for (int i = 0; i < 16; ++i) { a0[i] = 0.f; a12[i] = 0.f; }
        const size_t koff = ((size_t)bh * NN + n0 + ln) * DD + g * 8;
        #pragma unroll
        for (int kd = 0; kd < 4; ++kd) {
            uint4 uh = *(const uint4*)(khg + koff + kd * 16);
            uint4 ul = *(const uint4*)(klg + koff + kd * 16);
            half8 bh8, bl8;
            __builtin_memcpy(&bh8, &uh, 16);
            __builtin_memcpy(&bl8, &ul, 16);
            a0  = __builtin_amdgcn_mfma_f32_32x32x16_f16(qh[kd], bh8, a0, 0,0,0);
            a12 = __builtin_amdgcn_mfma_f32_32x32x16_f16(ql[kd], bh8, a12,0,0,0);
            a12 = __builtin_amdgcn_mfma_f32_32x32x16_f16(qh[kd], bl8, a12,0,0,0);
        }
        __syncthreads();   // pfr(prev step) reads complete everywhere
        #pragma unroll
        for (int r = 0; r < 16; ++r) {
            const int row = (r & 3) + 8 * (r >> 2) + 4 * g;
            const float p = __expf(fmaf(a12[r], C2INV, a0[r])) * rv[r];
            *((ushort_t*)&pfr[wv][ln >> 3][row] + (ln & 7)) = f2bf(p);
        }
        __syncthreads();   // P visible
        #pragma unroll
        for (int kh2 = 0; kh2 < 2; ++kh2) {
            short8 pa = pfr[wv][kh2 * 2 + g][ln];
            const ushort_t* vp0 = vt + ((size_t)bh * DD + ln) * NN + n0 + kh2 * 16 + g * 8;
            uint4 u0 = *(const uint4*)vp0;
            uint4 u1 = *(const uint4*)(vp0 + (size_t)32 * NN);
            short8 vb0, vb1;
            __builtin_memcpy(&vb0, &u0, 16);
            __builtin_memcpy(&vb1, &u1, 16);
            oacc0 = __builtin_amdgcn_mfma_f32_32x32x16_bf16(pa, vb0, oacc0, 0,0,0);
            oacc1 = __builtin_amdgcn_mfma_f32_32x32x16_bf16(pa, vb1, oacc1, 0,0,0);
        }
    }
    #pragma unroll
    for (int r = 0; r < 16; ++r) {
        const int row = (r & 3) + 8 * (r >> 2) + 4 * g;
        osum[wv][row][ln]      = oacc0[r];
        osum[wv][row][32 + ln] = oacc1[r];
    }
    __syncthreads();
    {
        const int qrow = t >> 3, d0 = (t & 7) * 8;
        float s[8] = {};
        #pragma unroll
        for (int w = 0; w < 4; ++w) {
            float4 a  = *(const float4*)&osum[w][qrow][d0];
            float4 b2 = *(const float4*)&osum[w][qrow][d0 + 4];
            s[0] += a.x;  s[1] += a.y;  s[2] += a.z;  s[3] += a.w;
            s[4] += b2.x; s[5] += b2.y; s[6] += b2.z; s[7] += b2.w;
        }
        float* op = opiv + ((size_t)(b * KPIV + r0 + qrow)) * CC + h * DD + d0;
        #pragma unroll
        for (int j = 0; j < 8; ++j) atomicAdd(op + j, s[j]);
    }
}

// ---------------- K7: output projection of pivot rows -> fp32 out -----------
__global__ __launch_bounds__(256) void proj_k(
    const float* __restrict__ opiv, const float* __restrict__ wp,
    const float* __restrict__ bp, float* __restrict__ out)
{
    __shared__ __attribute__((aligned(16))) float os[8][CC];
    const int t = threadIdx.x;
    const int r0 = blockIdx.x * 8;
    for (int f = t; f < 1024; f += 256) {
        const int rr = f >> 7, i = (f & 127) * 4;
        *(float4*)&os[rr][i] = *(const float4*)(opiv + (size_t)(r0 + rr) * CC + i);
    }
    __syncthreads();
    const int c0 = t;
    float acc0[8] = {}, acc1[8] = {};
    for (int i = 0; i < CC; ++i) {
        const float w0 = wp[(size_t)i * CC + c0];
        const float w1 = wp[(size_t)i * CC + c0 + 256];
        #pragma unroll
        for (int rr = 0; rr < 8; ++rr) {
            const float ov = os[rr][i];
            acc0[rr] = fmaf(ov, w0, acc0[rr]);
            acc1[rr] = fmaf(ov, w1, acc1[rr]);
        }
    }
    const float b0 = bp[c0], b1 = bp[c0 + 256];
    #pragma unroll
    for (int rr = 0; rr < 8; ++rr) {
        out[((size_t)(r0 + rr)) * CC + c0]       = acc0[rr] + b0;
        out[((size_t)(r0 + rr)) * CC + c0 + 256] = acc1[rr] + b1;
    }
}

extern "C" void kernel_launch(void* const* d_in, const int* in_sizes, int n_in,
                              void* d_out, int out_size, void* d_ws, size_t ws_size,
                              hipStream_t stream)
{
    const float* x     = (const float*)d_in[0];
    const float* wqkv  = (const float*)d_in[1];
    const float* wproj = (const float*)d_in[2];
    const float* bproj = (const float*)d_in[3];

    // workspace layout: ~52.8 MB total
    float*     q      = (float*)d_ws;                                  // 16.78 MB
    _Float16*  khg    = (_Float16*)(q + (size_t)BB * HH * NN * DD);    //  8.39 MB
    _Float16*  klg    = khg + (size_t)BB * HH * NN * DD;               //  8.39 MB
    ushort_t*  v      = (ushort_t*)(klg + (size_t)BB * HH * NN * DD);  //  8.39 MB (d-major)
    float*     l      = (float*)(v + (size_t)BB * HH * NN * DD);       //  0.26 MB
    float*     colsum = l + (size_t)BB * HH * NN;                      //  8.39 MB
    double*    imp    = (double*)(colsum + (size_t)512 * NN);          //  0.07 MB
    int*       idx    = (int*)(imp + BB * NN);                         //  4 KB
    float*     opiv   = (float*)(idx + BB * KPIV);                     //  2.10 MB
    float*     out    = (float*)d_out;

    const size_t need = (size_t)((char*)(opiv + (size_t)BB * KPIV * CC) - (char*)d_ws);
    if (ws_size < need) return;   // signature: out stays 0 -> absmax ~0.254

    qkv_gemm_k<<<dim3(64, 12), 256, 0, stream>>>(x, wqkv, q, khg, klg, v);
    pass_a_k<<<512, 256, 0, stream>>>(q, khg, klg, l);
    pass_b_k<<<512, 256, 0, stream>>>(q, khg, klg, l, colsum);
    imp_reduce_k<<<32, 256, 0, stream>>>(colsum, imp);
    topk_k<<<2, 1024, 0, stream>>>(imp, idx);
    hipMemsetAsync(opiv, 0, (size_t)BB * KPIV * CC * sizeof(float), stream);
    pass_c_k<<<512, 256, 0, stream>>>(q, khg, klg, v, l, idx, opiv);
    proj_k<<<128, 256, 0, stream>>>(opiv, wproj, bproj, out);
}